// Round 1
// baseline (178.232 us; speedup 1.0000x reference)
//
#include <hip/hip_runtime.h>
#include <hip/hip_bf16.h>

#define NN 50000
#define CC 64
#define KK 20

// ---------------------------------------------------------------------------
// Kernel 1: yA[n][c] = sum_ci (W1[c][ci]-W2[c][ci]) * x[ci][n] + b[c]
//           yB[n][c] = sum_ci  W2[c][ci]            * x[ci][n]
// where W = [W1 | W2], W[c][0..127].  Stored node-major so the edge kernel's
// per-(n,k) gather is 64 consecutive dwords (one coalesced 256B wave load).
// ---------------------------------------------------------------------------
__global__ __launch_bounds__(256) void prep_kernel(
    const float* __restrict__ x,   // [64][NN]
    const float* __restrict__ W,   // [64][128]
    const float* __restrict__ b,   // [64]
    float* __restrict__ yA,        // [NN][64]
    float* __restrict__ yB)        // [NN][64]
{
    __shared__ float At[64][65];   // At[ci][c] = W[c][ci] - W[c][64+ci]
    __shared__ float Bt[64][65];   // Bt[ci][c] = W[c][64+ci]
    __shared__ float xt[64][68];   // xt[ci][n_local], 68 keeps float4 rows 16B-aligned

    const int t = threadIdx.x;
    for (int i = t; i < 64 * 64; i += 256) {
        int c = i >> 6, ci = i & 63;
        float w1 = W[c * 128 + ci];
        float w2 = W[c * 128 + 64 + ci];
        At[ci][c] = w1 - w2;
        Bt[ci][c] = w2;
    }

    const int n0 = blockIdx.x * 64;
    const int g  = t >> 6;    // wave id 0..3
    const int nl = t & 63;
    #pragma unroll
    for (int i = 0; i < 16; i++) {
        int ci = i * 4 + g;
        int nn = n0 + nl;
        xt[ci][nl] = (nn < NN) ? x[ci * NN + nn] : 0.f;
    }
    __syncthreads();

    const int c = t & 63;
    float accA[16], accB[16];
    #pragma unroll
    for (int j = 0; j < 16; j++) { accA[j] = 0.f; accB[j] = 0.f; }

    for (int ci = 0; ci < 64; ci++) {
        float a  = At[ci][c];
        float w2 = Bt[ci][c];
        const float4* xr = reinterpret_cast<const float4*>(&xt[ci][g * 16]);
        #pragma unroll
        for (int q = 0; q < 4; q++) {
            float4 xv = xr[q];
            accA[q * 4 + 0] += a * xv.x;  accB[q * 4 + 0] += w2 * xv.x;
            accA[q * 4 + 1] += a * xv.y;  accB[q * 4 + 1] += w2 * xv.y;
            accA[q * 4 + 2] += a * xv.z;  accB[q * 4 + 2] += w2 * xv.z;
            accA[q * 4 + 3] += a * xv.w;  accB[q * 4 + 3] += w2 * xv.w;
        }
    }

    float bias = b[c];
    #pragma unroll
    for (int j = 0; j < 16; j++) {
        int n = n0 + g * 16 + j;
        if (n < NN) {
            yA[n * 64 + c] = accA[j] + bias;   // bias folded once (into yA only)
            yB[n * 64 + c] = accB[j];
        }
    }
}

// ---------------------------------------------------------------------------
// Kernel 2: per node n (one wave, lane = out-channel c):
//   scaler = tanh(sum_k att_w[k]*dis[n,k] + att_b) + 1
//   out[c][n] = max_k relu(yA[ei[n,k]][c] + yB[ej[n,k]][c]) * 2*sigmoid(-dis*scaler)
// Block = 4 waves = 64 nodes; results staged in LDS and written transposed so
// the out[c][n] store is coalesced over n.
// ---------------------------------------------------------------------------
__global__ __launch_bounds__(256) void edge_kernel(
    const float* __restrict__ yA,    // [NN][64]  (x_i path, edge_index[1])
    const float* __restrict__ yB,    // [NN][64]  (x_j path, edge_index[0])
    const int* __restrict__ ej,      // edge_index[0] : [NN][KK]
    const int* __restrict__ ei,      // edge_index[1] : [NN][KK]
    const float* __restrict__ dis,   // [NN][KK]
    const float* __restrict__ att_w, // [KK]
    const float* __restrict__ att_b, // [1]
    float* __restrict__ out)         // [64][NN]
{
    __shared__ float tile[64][65];

    const int t    = threadIdx.x;
    const int lane = t & 63;
    const int w    = t >> 6;       // wave 0..3
    const int n0   = blockIdx.x * 64;

    const float aw = (lane < KK) ? att_w[lane] : 0.f;
    const float ab = att_b[0];

    for (int s = 0; s < 16; s++) {
        const int nl = w * 16 + s;
        const int n  = n0 + nl;
        float m = 0.f;
        if (n < NN) {   // wave-uniform branch: n depends only on block/wave/s
            float d = 0.f; int ii = 0, jj = 0;
            if (lane < KK) {
                d  = dis[n * KK + lane];
                ii = ei[n * KK + lane];
                jj = ej[n * KK + lane];
            }
            // scaler = tanh(sum att_w*dis + att_b) + 1   (wave-sum, lanes>=20 add 0)
            float p = aw * d;
            #pragma unroll
            for (int off = 32; off > 0; off >>= 1) p += __shfl_down(p, off);
            const float scaler = tanhf(__shfl(p, 0) + ab) + 1.0f;

            #pragma unroll
            for (int k = 0; k < KK; k++) {
                const int   i_k = __shfl(ii, k);
                const int   j_k = __shfl(jj, k);
                const float d_k = __shfl(d, k);
                float v = yA[i_k * 64 + lane] + yB[j_k * 64 + lane];
                v = fmaxf(v, 0.f);
                const float sup = 2.0f / (1.0f + __expf(d_k * scaler));
                m = fmaxf(m, v * sup);   // all candidates >= 0, so init m=0 is exact
            }
        }
        tile[nl][lane] = m;
    }
    __syncthreads();

    #pragma unroll
    for (int it = 0; it < 16; it++) {
        const int c  = it * 4 + w;
        const int nn = n0 + (t & 63);
        if (nn < NN) out[c * NN + nn] = tile[t & 63][c];
    }
}

extern "C" void kernel_launch(void* const* d_in, const int* in_sizes, int n_in,
                              void* d_out, int out_size, void* d_ws, size_t ws_size,
                              hipStream_t stream) {
    const float* x     = (const float*)d_in[0];
    const int*   e     = (const int*)d_in[1];    // [2][NN][KK]
    const float* dis   = (const float*)d_in[2];
    const float* W     = (const float*)d_in[3];
    const float* b     = (const float*)d_in[4];
    const float* att_w = (const float*)d_in[5];
    const float* att_b = (const float*)d_in[6];
    float* out = (float*)d_out;

    float* yA = (float*)d_ws;                    // [NN][64]
    float* yB = yA + (size_t)NN * 64;            // [NN][64]  (needs 25.6 MB ws)

    const int grid = (NN + 63) / 64;             // 782
    prep_kernel<<<grid, 256, 0, stream>>>(x, W, b, yA, yB);
    edge_kernel<<<grid, 256, 0, stream>>>(yA, yB, e, e + NN * KK, dis,
                                          att_w, att_b, out);
}

// Round 2
// 143.855 us; speedup vs baseline: 1.2390x; 1.2390x over previous
//
#include <hip/hip_runtime.h>
#include <hip/hip_bf16.h>

#define NN 50000
#define CC 64
#define KK 20

static __device__ __forceinline__ ushort f2bf(float f) {
    unsigned int u = __float_as_uint(f);
    unsigned int r = (u + 0x7FFFu + ((u >> 16) & 1u)) >> 16;   // RNE
    return (ushort)r;
}
static __device__ __forceinline__ float bf2f(ushort v) {
    return __uint_as_float(((unsigned int)v) << 16);
}

// ---------------------------------------------------------------------------
// Kernel 1: yA[n][c] = sum_ci (W1[c][ci]-W2[c][ci]) * x[ci][n] + b[c]
//           yB[n][c] = sum_ci  W2[c][ci]            * x[ci][n]
// Stored node-major in bf16 so the edge kernel's per-(n,k) gather of a
// 64-channel column is 128 contiguous bytes (one coalesced wave load).
// ---------------------------------------------------------------------------
__global__ __launch_bounds__(256) void prep_kernel(
    const float* __restrict__ x,   // [64][NN]
    const float* __restrict__ W,   // [64][128]
    const float* __restrict__ b,   // [64]
    ushort* __restrict__ yA,       // [NN][64] bf16
    ushort* __restrict__ yB)       // [NN][64] bf16
{
    __shared__ float At[64][65];   // At[ci][c] = W[c][ci] - W[c][64+ci]
    __shared__ float Bt[64][65];   // Bt[ci][c] = W[c][64+ci]
    __shared__ float xt[64][68];   // xt[ci][n_local]

    const int t = threadIdx.x;
    for (int i = t; i < 64 * 64; i += 256) {
        int c = i >> 6, ci = i & 63;
        float w1 = W[c * 128 + ci];
        float w2 = W[c * 128 + 64 + ci];
        At[ci][c] = w1 - w2;
        Bt[ci][c] = w2;
    }

    const int n0 = blockIdx.x * 64;
    const int g  = t >> 6;    // wave id 0..3
    const int nl = t & 63;
    #pragma unroll
    for (int i = 0; i < 16; i++) {
        int ci = i * 4 + g;
        int nn = n0 + nl;
        xt[ci][nl] = (nn < NN) ? x[ci * NN + nn] : 0.f;
    }
    __syncthreads();

    const int c = t & 63;
    float accA[16], accB[16];
    #pragma unroll
    for (int j = 0; j < 16; j++) { accA[j] = 0.f; accB[j] = 0.f; }

    for (int ci = 0; ci < 64; ci++) {
        float a  = At[ci][c];
        float w2 = Bt[ci][c];
        const float4* xr = reinterpret_cast<const float4*>(&xt[ci][g * 16]);
        #pragma unroll
        for (int q = 0; q < 4; q++) {
            float4 xv = xr[q];
            accA[q * 4 + 0] += a * xv.x;  accB[q * 4 + 0] += w2 * xv.x;
            accA[q * 4 + 1] += a * xv.y;  accB[q * 4 + 1] += w2 * xv.y;
            accA[q * 4 + 2] += a * xv.z;  accB[q * 4 + 2] += w2 * xv.z;
            accA[q * 4 + 3] += a * xv.w;  accB[q * 4 + 3] += w2 * xv.w;
        }
    }

    float bias = b[c];
    #pragma unroll
    for (int j = 0; j < 16; j++) {
        int n = n0 + g * 16 + j;
        if (n < NN) {
            yA[n * 64 + c] = f2bf(accA[j] + bias);   // bias folded into yA only
            yB[n * 64 + c] = f2bf(accB[j]);
        }
    }
}

// ---------------------------------------------------------------------------
// Kernel 2: 16 nodes/block (4 waves, 4 nodes/wave), grid 3125 -> full wave
// occupancy. Per node: sup_k precomputed once in lanes<20, broadcast via
// readlane in the k-loop. Gather = two 128B bf16 columns per (n,k).
// ---------------------------------------------------------------------------
__global__ __launch_bounds__(256) void edge_kernel(
    const ushort* __restrict__ yA,   // [NN][64] bf16  (x_i path, edge_index[1])
    const ushort* __restrict__ yB,   // [NN][64] bf16  (x_j path, edge_index[0])
    const int* __restrict__ ej,      // edge_index[0] : [NN][KK]
    const int* __restrict__ ei,      // edge_index[1] : [NN][KK]
    const float* __restrict__ dis,   // [NN][KK]
    const float* __restrict__ att_w, // [KK]
    const float* __restrict__ att_b, // [1]
    float* __restrict__ out)         // [64][NN]
{
    __shared__ float tile[16][65];

    const int t    = threadIdx.x;
    const int lane = t & 63;
    const int w    = t >> 6;            // wave 0..3
    const int n0   = blockIdx.x * 16;   // grid = 3125, no tail (3125*16 = 50000)

    const float aw = (lane < KK) ? att_w[lane] : 0.f;
    const float ab = att_b[0];

    #pragma unroll
    for (int s = 0; s < 4; s++) {
        const int nl = w * 4 + s;
        const int n  = n0 + nl;

        float d = 0.f; int ii = 0, jj = 0;
        if (lane < KK) {
            d  = dis[n * KK + lane];
            ii = ei[n * KK + lane];
            jj = ej[n * KK + lane];
        }
        // scaler = tanh(sum_k att_w*dis + att_b) + 1 ; lanes >= 20 contribute 0.
        float p = aw * d;
        #pragma unroll
        for (int off = 16; off > 0; off >>= 1) p += __shfl_down(p, off);
        const float scaler = tanhf(__shfl(p, 0) + ab) + 1.0f;
        // sup_k = 2*sigmoid(-d*scaler), computed once per node (lanes < 20)
        const float sup = 2.0f / (1.0f + __expf(d * scaler));

        float m = 0.f;
        #pragma unroll
        for (int k = 0; k < KK; k++) {
            const int   i_k = __shfl(ii, k);
            const int   j_k = __shfl(jj, k);
            const float s_k = __shfl(sup, k);
            float a = bf2f(yA[(size_t)i_k * 64 + lane]);
            float bv = bf2f(yB[(size_t)j_k * 64 + lane]);
            float v = fmaxf(a + bv, 0.f);
            m = fmaxf(m, v * s_k);   // all candidates >= 0, so m=0 init is exact
        }
        tile[nl][lane] = m;
    }
    __syncthreads();

    // out[c][n0..n0+15], coalesced in 64B segments; each thread stores 4.
    #pragma unroll
    for (int it = 0; it < 4; it++) {
        const int c  = it * 16 + (t >> 4);
        const int nl = t & 15;
        out[(size_t)c * NN + n0 + nl] = tile[nl][c];
    }
}

extern "C" void kernel_launch(void* const* d_in, const int* in_sizes, int n_in,
                              void* d_out, int out_size, void* d_ws, size_t ws_size,
                              hipStream_t stream) {
    const float* x     = (const float*)d_in[0];
    const int*   e     = (const int*)d_in[1];    // [2][NN][KK]
    const float* dis   = (const float*)d_in[2];
    const float* W     = (const float*)d_in[3];
    const float* b     = (const float*)d_in[4];
    const float* att_w = (const float*)d_in[5];
    const float* att_b = (const float*)d_in[6];
    float* out = (float*)d_out;

    ushort* yA = (ushort*)d_ws;                  // [NN][64] bf16
    ushort* yB = yA + (size_t)NN * 64;           // [NN][64] bf16 (12.8 MB total)

    prep_kernel<<<(NN + 63) / 64, 256, 0, stream>>>(x, W, b, yA, yB);
    edge_kernel<<<NN / 16, 256, 0, stream>>>(yA, yB, e, e + NN * KK, dis,
                                             att_w, att_b, out);
}

// Round 3
// 133.807 us; speedup vs baseline: 1.3320x; 1.0751x over previous
//
#include <hip/hip_runtime.h>
#include <hip/hip_bf16.h>

#define NN 50000
#define CC 64
#define KK 20

static __device__ __forceinline__ ushort f2bf(float f) {
    unsigned int u = __float_as_uint(f);
    unsigned int r = (u + 0x7FFFu + ((u >> 16) & 1u)) >> 16;   // RNE
    return (ushort)r;
}
static __device__ __forceinline__ float bfl(unsigned int u) {   // low bf16 -> f32
    return __uint_as_float(u << 16);
}
static __device__ __forceinline__ float bfh(unsigned int u) {   // high bf16 -> f32
    return __uint_as_float(u & 0xffff0000u);
}

// ---------------------------------------------------------------------------
// Kernel 1: yA[n][c] = sum_ci (W1[c][ci]-W2[c][ci]) * x[ci][n] + b[c]
//           yB[n][c] = sum_ci  W2[c][ci]            * x[ci][n]
// Stored node-major bf16: one node's 64 channels = 128 B = one cache line.
// ---------------------------------------------------------------------------
__global__ __launch_bounds__(256) void prep_kernel(
    const float* __restrict__ x,   // [64][NN]
    const float* __restrict__ W,   // [64][128]
    const float* __restrict__ b,   // [64]
    ushort* __restrict__ yA,       // [NN][64] bf16
    ushort* __restrict__ yB)       // [NN][64] bf16
{
    __shared__ float At[64][65];
    __shared__ float Bt[64][65];
    __shared__ float xt[64][68];

    const int t = threadIdx.x;
    for (int i = t; i < 64 * 64; i += 256) {
        int c = i >> 6, ci = i & 63;
        float w1 = W[c * 128 + ci];
        float w2 = W[c * 128 + 64 + ci];
        At[ci][c] = w1 - w2;
        Bt[ci][c] = w2;
    }

    const int n0 = blockIdx.x * 64;
    const int g  = t >> 6;
    const int nl = t & 63;
    #pragma unroll
    for (int i = 0; i < 16; i++) {
        int ci = i * 4 + g;
        int nn = n0 + nl;
        xt[ci][nl] = (nn < NN) ? x[ci * NN + nn] : 0.f;
    }
    __syncthreads();

    const int c = t & 63;
    float accA[16], accB[16];
    #pragma unroll
    for (int j = 0; j < 16; j++) { accA[j] = 0.f; accB[j] = 0.f; }

    for (int ci = 0; ci < 64; ci++) {
        float a  = At[ci][c];
        float w2 = Bt[ci][c];
        const float4* xr = reinterpret_cast<const float4*>(&xt[ci][g * 16]);
        #pragma unroll
        for (int q = 0; q < 4; q++) {
            float4 xv = xr[q];
            accA[q * 4 + 0] += a * xv.x;  accB[q * 4 + 0] += w2 * xv.x;
            accA[q * 4 + 1] += a * xv.y;  accB[q * 4 + 1] += w2 * xv.y;
            accA[q * 4 + 2] += a * xv.z;  accB[q * 4 + 2] += w2 * xv.z;
            accA[q * 4 + 3] += a * xv.w;  accB[q * 4 + 3] += w2 * xv.w;
        }
    }

    float bias = b[c];
    #pragma unroll
    for (int j = 0; j < 16; j++) {
        int n = n0 + g * 16 + j;
        if (n < NN) {
            yA[n * 64 + c] = f2bf(accA[j] + bias);
            yB[n * 64 + c] = f2bf(accB[j]);
        }
    }
}

// ---------------------------------------------------------------------------
// Kernel 2: 16 nodes/block, 4 nodes/wave. Slot-parallel gather: lane =
// (g,l) with g=lane>>4 the edge slot, l=lane&15 the channel quad. One
// uint2 (8B, 4 bf16 channels) per lane -> one wave load fetches 4 edges'
// 128B columns. 5 iterations cover k=0..19; max-over-k finishes with two
// shfl_xor reductions across slots.
// ---------------------------------------------------------------------------
__global__ __launch_bounds__(256) void edge_kernel(
    const ushort* __restrict__ yA,   // [NN][64] bf16  (x_i path, edge_index[1])
    const ushort* __restrict__ yB,   // [NN][64] bf16  (x_j path, edge_index[0])
    const int* __restrict__ ej,      // edge_index[0] : [NN][KK]
    const int* __restrict__ ei,      // edge_index[1] : [NN][KK]
    const float* __restrict__ dis,   // [NN][KK]
    const float* __restrict__ att_w, // [KK]
    const float* __restrict__ att_b, // [1]
    float* __restrict__ out)         // [64][NN]
{
    __shared__ float tile[16][68];   // stride 68 floats = 272B, keeps float4 aligned

    const int t    = threadIdx.x;
    const int lane = t & 63;
    const int w    = t >> 6;            // wave 0..3
    const int g    = lane >> 4;         // edge slot 0..3
    const int l    = lane & 15;         // channel quad: channels 4l..4l+3
    const int n0   = blockIdx.x * 16;   // grid 3125, no tail
    const int nb   = n0 + w * 4;

    const float aw = (lane < KK) ? att_w[lane] : 0.f;
    const float ab = att_b[0];

    // Phase 1: load all 4 nodes' edge data first (12 loads in flight), then
    // the (serial) scaler reductions per node.
    float d4[4]; int ii4[4], jj4[4];
    #pragma unroll
    for (int s = 0; s < 4; s++) {
        const int n = nb + s;
        float d = 0.f; int ii = 0, jj = 0;
        if (lane < KK) {
            d  = dis[n * KK + lane];
            ii = ei[n * KK + lane];
            jj = ej[n * KK + lane];
        }
        d4[s] = d; ii4[s] = ii; jj4[s] = jj;
    }

    float sup4[4];
    #pragma unroll
    for (int s = 0; s < 4; s++) {
        float p = aw * d4[s];
        #pragma unroll
        for (int off = 16; off > 0; off >>= 1) p += __shfl_down(p, off);
        const float scaler = tanhf(__shfl(p, 0) + ab) + 1.0f;
        sup4[s] = 2.0f / (1.0f + __expf(d4[s] * scaler));  // valid lanes < 20
    }

    const uint2* A2 = (const uint2*)yA;   // 16 uint2 per node column
    const uint2* B2 = (const uint2*)yB;

    #pragma unroll
    for (int s = 0; s < 4; s++) {
        float4 m = {0.f, 0.f, 0.f, 0.f};
        #pragma unroll
        for (int kb = 0; kb < 5; kb++) {
            const int   src = kb * 4 + g;          // edge k handled by this slot
            const int   i_k = __shfl(ii4[s], src);
            const int   j_k = __shfl(jj4[s], src);
            const float sp  = __shfl(sup4[s], src);
            const uint2 a = A2[(size_t)i_k * 16 + l];
            const uint2 bb = B2[(size_t)j_k * 16 + l];
            float v;
            v = fmaxf(bfl(a.x) + bfl(bb.x), 0.f) * sp;  m.x = fmaxf(m.x, v);
            v = fmaxf(bfh(a.x) + bfh(bb.x), 0.f) * sp;  m.y = fmaxf(m.y, v);
            v = fmaxf(bfl(a.y) + bfl(bb.y), 0.f) * sp;  m.z = fmaxf(m.z, v);
            v = fmaxf(bfh(a.y) + bfh(bb.y), 0.f) * sp;  m.w = fmaxf(m.w, v);
        }
        // max across the 4 slots (lanes with equal l)
        #pragma unroll
        for (int mask = 16; mask <= 32; mask <<= 1) {
            m.x = fmaxf(m.x, __shfl_xor(m.x, mask));
            m.y = fmaxf(m.y, __shfl_xor(m.y, mask));
            m.z = fmaxf(m.z, __shfl_xor(m.z, mask));
            m.w = fmaxf(m.w, __shfl_xor(m.w, mask));
        }
        if (g == 0) *(float4*)&tile[w * 4 + s][l * 4] = m;
    }
    __syncthreads();

    // out[c][n0..n0+15]; 2-way LDS aliasing only (free).
    #pragma unroll
    for (int it = 0; it < 4; it++) {
        const int c  = it * 16 + (t >> 4);
        const int nl = t & 15;
        out[(size_t)c * NN + n0 + nl] = tile[nl][c];
    }
}

extern "C" void kernel_launch(void* const* d_in, const int* in_sizes, int n_in,
                              void* d_out, int out_size, void* d_ws, size_t ws_size,
                              hipStream_t stream) {
    const float* x     = (const float*)d_in[0];
    const int*   e     = (const int*)d_in[1];    // [2][NN][KK]
    const float* dis   = (const float*)d_in[2];
    const float* W     = (const float*)d_in[3];
    const float* b     = (const float*)d_in[4];
    const float* att_w = (const float*)d_in[5];
    const float* att_b = (const float*)d_in[6];
    float* out = (float*)d_out;

    ushort* yA = (ushort*)d_ws;                  // [NN][64] bf16
    ushort* yB = yA + (size_t)NN * 64;           // [NN][64] bf16 (12.8 MB total)

    prep_kernel<<<(NN + 63) / 64, 256, 0, stream>>>(x, W, b, yA, yB);
    edge_kernel<<<NN / 16, 256, 0, stream>>>(yA, yB, e, e + NN * KK, dis,
                                             att_w, att_b, out);
}